// Round 2
// baseline (209.846 us; speedup 1.0000x reference)
//
#include <hip/hip_runtime.h>

// ResidualVQ forward: out[n] = codebook[argmin_k(-2 x.c_k + ||c_k||^2)]
// (straight-through: out == quantized; SCALE_FACTOR == 1.0)
//
// v2: x row pinned in VGPRs; codebook streamed through double-buffered LDS
// tiles via global_load_lds(16B); broadcast ds_read_b128 feeds v_fmac_f32.

constexpr int D = 128;       // embedding dim
constexpr int ROWS = 64;     // rows per block (= lanes per wave)
constexpr int TK = 64;       // codes per LDS tile (32 KB fp32)
constexpr int WAVES = 4;     // 256-thread block
constexpr int KPW = TK / WAVES;  // codes per wave per tile = 16
constexpr int KMAX = 1024;

// --- kernel 0: codebook squared norms into ws ---
__global__ __launch_bounds__(256) void cnorm_kernel(const float* __restrict__ cb,
                                                    float* __restrict__ cnorm, int K) {
    int k = blockIdx.x * blockDim.x + threadIdx.x;
    if (k >= K) return;
    const float4* c = (const float4*)(cb + (size_t)k * D);
    float s0 = 0.f, s1 = 0.f, s2 = 0.f, s3 = 0.f;
#pragma unroll
    for (int i = 0; i < D / 4; ++i) {
        float4 v = c[i];
        s0 = fmaf(v.x, v.x, s0);
        s1 = fmaf(v.y, v.y, s1);
        s2 = fmaf(v.z, v.z, s2);
        s3 = fmaf(v.w, v.w, s3);
    }
    cnorm[k] = (s0 + s1) + (s2 + s3);
}

// stage one 64x128 fp32 codebook tile (32 KB) into LDS, 256 threads.
// global_load_lds: LDS dest = wave-uniform base + lane*16 (HW), global src per-lane.
__device__ __forceinline__ void stage_tile(const float* __restrict__ src,
                                           float* dst_lds, int wave, int lane) {
    const char* g = (const char*)src + wave * 8192 + lane * 16;
    char* l = (char*)dst_lds + wave * 8192;
#pragma unroll
    for (int i = 0; i < 8; ++i) {
        __builtin_amdgcn_global_load_lds(
            (const __attribute__((address_space(1))) uint32_t*)(g + i * 1024),
            (__attribute__((address_space(3))) uint32_t*)(l + i * 1024),
            16, 0, 0);
    }
}

__global__ __launch_bounds__(256) void vq_argmin_gather(const float* __restrict__ x,
                                                        const float* __restrict__ cb,
                                                        const float* __restrict__ cnorm,
                                                        float* __restrict__ out,
                                                        int N, int K) {
    __shared__ float cbt[2][TK * D];       // 64 KB double-buffered codebook tile
    __shared__ float cn[KMAX];             // 4 KB codebook norms
    __shared__ float sdist[WAVES][ROWS];
    __shared__ int sidx[WAVES][ROWS];
    __shared__ int fidx[ROWS];

    const int tid = threadIdx.x;
    const int lane = tid & 63;
    const int wave = tid >> 6;
    int row = blockIdx.x * ROWS + lane;
    if (row >= N) row = N - 1;  // N = 32768 is a multiple of 64; safety clamp

    // ---- x row into VGPRs, then pin so the compiler can't rematerialize ----
    float xr[D];
    {
        const float4* xp = (const float4*)(x + (size_t)row * D);
#pragma unroll
        for (int i = 0; i < D / 4; ++i) {
            float4 v = xp[i];
            xr[4 * i + 0] = v.x;
            xr[4 * i + 1] = v.y;
            xr[4 * i + 2] = v.z;
            xr[4 * i + 3] = v.w;
        }
    }
#pragma unroll
    for (int i = 0; i < D; ++i) asm volatile("" : "+v"(xr[i]));

    // ---- norms into LDS; stage tile 0 ----
    for (int i = tid; i < K; i += 256) cn[i] = cnorm[i];
    stage_tile(cb, &cbt[0][0], wave, lane);
    __syncthreads();  // compiler drains vmcnt+lgkmcnt before s_barrier

    const int NT = K / TK;  // 16 tiles
    float best = 3.4e38f;
    int bidx = 0x7fffffff;
    int buf = 0;

    for (int t = 0; t < NT; ++t) {
        // prefetch next tile into the other buffer (loads fly during compute)
        if (t + 1 < NT) stage_tile(cb + (size_t)(t + 1) * TK * D, &cbt[buf ^ 1][0], wave, lane);

        const int kbase = t * TK + wave * KPW;
        const float* crow = &cbt[buf][(wave * KPW) * D];
#pragma unroll 2
        for (int j = 0; j < KPW; ++j) {
            float d0 = 0.f, d1 = 0.f, d2 = 0.f, d3 = 0.f;
            const float4* c4 = (const float4*)(crow + j * D);
#pragma unroll
            for (int i = 0; i < D / 4; ++i) {
                float4 cv = c4[i];  // broadcast ds_read_b128, conflict-free
                d0 = fmaf(xr[4 * i + 0], cv.x, d0);
                d1 = fmaf(xr[4 * i + 1], cv.y, d1);
                d2 = fmaf(xr[4 * i + 2], cv.z, d2);
                d3 = fmaf(xr[4 * i + 3], cv.w, d3);
            }
            float dot = (d0 + d1) + (d2 + d3);
            int k = kbase + j;
            float dist = fmaf(-2.0f, dot, cn[k]);
            if (dist < best) {  // strict < keeps lowest index (k ascending per wave)
                best = dist;
                bidx = k;
            }
        }
        __syncthreads();  // waits vmcnt(0): next tile fully landed; LDS reads done
        buf ^= 1;
    }

    // ---- cross-wave argmin ----
    sdist[wave][lane] = best;
    sidx[wave][lane] = bidx;
    __syncthreads();
    if (wave == 0) {
        float b = sdist[0][lane];
        int bi = sidx[0][lane];
#pragma unroll
        for (int w = 1; w < WAVES; ++w) {
            float dw = sdist[w][lane];
            int iw = sidx[w][lane];
            if (dw < b || (dw == b && iw < bi)) {
                b = dw;
                bi = iw;
            }
        }
        fidx[lane] = bi;
    }
    __syncthreads();

    // ---- gather: 256 threads write 64 rows x 128 floats, coalesced float4 ----
    const int r = tid >> 2;
    const int ch = tid & 3;
    int grow = blockIdx.x * ROWS + r;
    if (grow >= N) grow = N - 1;
    const int src = fidx[r];
    const float4* cs = (const float4*)(cb + (size_t)src * D + ch * 32);
    float4* od = (float4*)(out + (size_t)grow * D + ch * 32);
#pragma unroll
    for (int i = 0; i < 8; ++i) od[i] = cs[i];
}

extern "C" void kernel_launch(void* const* d_in, const int* in_sizes, int n_in,
                              void* d_out, int out_size, void* d_ws, size_t ws_size,
                              hipStream_t stream) {
    const float* x = (const float*)d_in[0];
    const float* cb = (const float*)d_in[1];
    float* out = (float*)d_out;
    const int N = in_sizes[0] / D;
    const int K = in_sizes[1] / D;
    float* cnorm = (float*)d_ws;  // K floats

    hipLaunchKernelGGL(cnorm_kernel, dim3((K + 255) / 256), dim3(256), 0, stream,
                       cb, cnorm, K);
    hipLaunchKernelGGL(vq_argmin_gather, dim3((N + ROWS - 1) / ROWS), dim3(256), 0,
                       stream, x, cb, cnorm, out, N, K);
}

// Round 3
// 136.544 us; speedup vs baseline: 1.5368x; 1.5368x over previous
//
#include <hip/hip_runtime.h>

// ResidualVQ forward: out[n] = codebook[argmin_k(-2 x.c_k + ||c_k||^2)]
// (straight-through: out == quantized; SCALE_FACTOR == 1.0)
//
// v3: register-blocked fp32 VALU GEMM. Thread tile 8 rows x 16 codes
// (128 accumulators). x transposed once into LDS (xT[k][row]); codebook
// streamed in transposed 16-dim chunks, double-buffered, reg-staged with
// early global-load issue. Argmin amortized: once per 512-code block.

constexpr int D = 128;        // embedding dim
constexpr int BR = 128;       // rows per block
constexpr int BC = 512;       // codes per code-block iteration
constexpr int KCH = 16;       // dims per staged codebook chunk
constexpr int NCH = D / KCH;  // 8 chunks per code-block
constexpr int NTH = 512;      // threads per block (8 waves)

// --- kernel 0: codebook squared norms into ws ---
__global__ __launch_bounds__(256) void cnorm_kernel(const float* __restrict__ cb,
                                                    float* __restrict__ cnorm, int K) {
    int k = blockIdx.x * blockDim.x + threadIdx.x;
    if (k >= K) return;
    const float4* c = (const float4*)(cb + (size_t)k * D);
    float s0 = 0.f, s1 = 0.f, s2 = 0.f, s3 = 0.f;
#pragma unroll
    for (int i = 0; i < D / 4; ++i) {
        float4 v = c[i];
        s0 = fmaf(v.x, v.x, s0);
        s1 = fmaf(v.y, v.y, s1);
        s2 = fmaf(v.z, v.z, s2);
        s3 = fmaf(v.w, v.w, s3);
    }
    cnorm[k] = (s0 + s1) + (s2 + s3);
}

__global__ __launch_bounds__(NTH, 2) void vq_kernel(const float* __restrict__ x,
                                                    const float* __restrict__ cb,
                                                    const float* __restrict__ cnorm,
                                                    float* __restrict__ out,
                                                    int N, int K) {
    __shared__ float xT[D][BR + 4];     // 128 x 132 fp32 = 67.6 KB (pad: write-conflict relief)
    __shared__ float cbT[2][KCH][BC];   // 2 x 16 x 512 = 64 KB, double-buffered
    __shared__ float cn[1024];          // codebook norms (K <= 1024)
    __shared__ int fidx[BR];

    const int tid = threadIdx.x;
    const int tx = tid & 31;    // code-group index within block tile
    const int ty = tid >> 5;    // row-group index 0..15
    const int row0 = blockIdx.x * BR;

    // ---- stage xT: x[row0+r][k] -> xT[k][r] (coalesced 64B reads, 2-way-free writes) ----
    {
        const int r = tid >> 2;  // 0..127
        const int q = tid & 3;
        int rg = row0 + r;
        if (rg >= N) rg = N - 1;
        const float* xrow = x + (size_t)rg * D;
#pragma unroll
        for (int j = 0; j < 8; ++j) {
            const int kq = q + 4 * j;  // float4-quad index 0..31
            float4 v = *(const float4*)(xrow + kq * 4);
            xT[kq * 4 + 0][r] = v.x;
            xT[kq * 4 + 1][r] = v.y;
            xT[kq * 4 + 2][r] = v.z;
            xT[kq * 4 + 3][r] = v.w;
        }
    }
    // ---- stage norms ----
    for (int i = tid; i < K; i += NTH) cn[i] = cnorm[i];
    // ---- stage codebook chunk 0 (codes 0..511, dims 0..15), transposed ----
    {
        const float* src = cb + (size_t)tid * D;
        float4 c0 = *(const float4*)(src + 0);
        float4 c1 = *(const float4*)(src + 4);
        float4 c2 = *(const float4*)(src + 8);
        float4 c3 = *(const float4*)(src + 12);
        float tmp[16] = {c0.x, c0.y, c0.z, c0.w, c1.x, c1.y, c1.z, c1.w,
                         c2.x, c2.y, c2.z, c2.w, c3.x, c3.y, c3.z, c3.w};
#pragma unroll
        for (int kk = 0; kk < KCH; ++kk) cbT[0][kk][tid] = tmp[kk];
    }
    __syncthreads();

    float acc[8][16];
    float best[8];
    int bidx[8];
#pragma unroll
    for (int rr = 0; rr < 8; ++rr) {
        best[rr] = 3.4e38f;
        bidx[rr] = 0;
#pragma unroll
        for (int cc = 0; cc < 16; ++cc) acc[rr][cc] = 0.f;
    }

    const int NCBB = K / BC;        // 2 code-blocks
    const int TOT = NCBB * NCH;     // 16 chunks total

    for (int ch = 0; ch < TOT; ++ch) {
        const int cur = ch & 1;
        // ---- issue next-chunk global loads EARLY (fly under the compute) ----
        float4 n0, n1, n2, n3;
        const bool hasNext = (ch + 1 < TOT);
        if (hasNext) {
            const int nb = (ch + 1) >> 3;          // next code-block
            const int nk = ((ch + 1) & 7) * KCH;   // next chunk's base dim
            const float* src = cb + (size_t)(nb * BC + tid) * D + nk;
            n0 = *(const float4*)(src + 0);
            n1 = *(const float4*)(src + 4);
            n2 = *(const float4*)(src + 8);
            n3 = *(const float4*)(src + 12);
        }

        // ---- compute 16 k-steps: 10 LDS reads + 128 fmacs each ----
        const int kbase = (ch & 7) * KCH;
#pragma unroll 8
        for (int kk = 0; kk < KCH; ++kk) {
            const int kg = kbase + kk;
            const float4 a0 = *(const float4*)&xT[kg][ty * 8];      // 8 rows of x at dim kg
            const float4 a1 = *(const float4*)&xT[kg][ty * 8 + 4];  // (broadcast, conflict-free)
            float xv[8] = {a0.x, a0.y, a0.z, a0.w, a1.x, a1.y, a1.z, a1.w};
            float2 cv[8];
#pragma unroll
            for (int j = 0; j < 8; ++j)  // 16 codes: lane-contiguous b64, conflict-free
                cv[j] = *(const float2*)&cbT[cur][kk][tx * 2 + 64 * j];
#pragma unroll
            for (int rr = 0; rr < 8; ++rr) {
#pragma unroll
                for (int j = 0; j < 8; ++j) {
                    acc[rr][2 * j + 0] = fmaf(xv[rr], cv[j].x, acc[rr][2 * j + 0]);
                    acc[rr][2 * j + 1] = fmaf(xv[rr], cv[j].y, acc[rr][2 * j + 1]);
                }
            }
        }

        // ---- per-code-block argmin epilogue (amortized over 128 k-steps) ----
        if ((ch & 7) == 7) {
            const int cbb = ch >> 3;
#pragma unroll
            for (int j = 0; j < 8; ++j) {
#pragma unroll
                for (int i = 0; i < 2; ++i) {
                    const int c = cbb * BC + 64 * j + tx * 2 + i;
                    const float cnv = cn[c];
#pragma unroll
                    for (int rr = 0; rr < 8; ++rr) {
                        float dist = fmaf(-2.0f, acc[rr][2 * j + i], cnv);
                        if (dist < best[rr]) {  // strict <: lowest index wins (codes ascend)
                            best[rr] = dist;
                            bidx[rr] = c;
                        }
                        acc[rr][2 * j + i] = 0.f;  // re-zero for next code-block
                    }
                }
            }
        }

        __syncthreads();  // everyone done reading cbT[cur]
        if (hasNext) {
            const int nxt = cur ^ 1;
            float tmp[16] = {n0.x, n0.y, n0.z, n0.w, n1.x, n1.y, n1.z, n1.w,
                             n2.x, n2.y, n2.z, n2.w, n3.x, n3.y, n3.z, n3.w};
#pragma unroll
            for (int kk = 0; kk < KCH; ++kk) cbT[nxt][kk][tid] = tmp[kk];
            __syncthreads();  // chunk landed before next compute reads it
        }
    }

    // ---- reduce best across the 32 tx-threads (half-wave shuffle) ----
#pragma unroll
    for (int rr = 0; rr < 8; ++rr) {
        float d = best[rr];
        int ii = bidx[rr];
#pragma unroll
        for (int off = 16; off >= 1; off >>= 1) {
            float od = __shfl_xor(d, off);
            int oi = __shfl_xor(ii, off);
            if (od < d || (od == d && oi < ii)) {
                d = od;
                ii = oi;
            }
        }
        if (tx == 0) fidx[ty * 8 + rr] = ii;
    }
    __syncthreads();

    // ---- gather: out[row] = codebook[fidx[row]] (L2-resident reads) ----
    {
        const int r = tid >> 2;
        const int q = tid & 3;  // 32-float chunk within the row
        int grow = row0 + r;
        if (grow >= N) grow = N - 1;
        const int src = fidx[r];
        const float4* cs = (const float4*)(cb + (size_t)src * D + q * 32);
        float4* od = (float4*)(out + (size_t)grow * D + q * 32);
#pragma unroll
        for (int i = 0; i < 8; ++i) od[i] = cs[i];
    }
}

extern "C" void kernel_launch(void* const* d_in, const int* in_sizes, int n_in,
                              void* d_out, int out_size, void* d_ws, size_t ws_size,
                              hipStream_t stream) {
    const float* x = (const float*)d_in[0];
    const float* cb = (const float*)d_in[1];
    float* out = (float*)d_out;
    const int N = in_sizes[0] / D;
    const int K = in_sizes[1] / D;
    float* cnorm = (float*)d_ws;  // K floats

    hipLaunchKernelGGL(cnorm_kernel, dim3((K + 255) / 256), dim3(256), 0, stream,
                       cb, cnorm, K);
    hipLaunchKernelGGL(vq_kernel, dim3((N + BR - 1) / BR), dim3(NTH), 0, stream,
                       x, cb, cnorm, out, N, K);
}

// Round 4
// 78.186 us; speedup vs baseline: 2.6839x; 1.7464x over previous
//
#include <hip/hip_runtime.h>

// ResidualVQ forward: out[n] = codebook[argmin_k(-2 x.c_k + ||c_k||^2)]
// v4: split-bf16 MFMA GEMM (hi*hi + hi*lo + lo*hi, fp32 accum) for approximate
// scores + provably-safe margin candidate list + exact fp32 recheck.
// |approx err| <= ~4e-3 << MARGIN/2, so the true winner is always a candidate.

typedef short bfrag __attribute__((ext_vector_type(8)));  // 8 bf16 = 4 VGPR
typedef float f32x4 __attribute__((ext_vector_type(4)));

constexpr int D = 128;       // embedding dim
constexpr int BR = 128;      // rows per block  -> grid = 256 = 1 block/CU
constexpr int TC = 64;       // codes per LDS tile
constexpr int NTILE = 16;    // 1024 / 64
constexpr int NTH = 512;     // 8 waves: 4 row-groups x 2 code-halves
constexpr int LCAP = 2048;   // candidate list capacity (expect ~135)
#define MARGIN 0.0625f

__device__ __forceinline__ unsigned fenc(float f) {  // order-preserving f32->u32
    unsigned u = __float_as_uint(f);
    return (u & 0x80000000u) ? ~u : (u | 0x80000000u);
}
__device__ __forceinline__ float fdec(unsigned e) {
    unsigned u = (e & 0x80000000u) ? (e & 0x7FFFFFFFu) : ~e;
    return __uint_as_float(u);
}
__device__ __forceinline__ unsigned cvtpk(float a, float b) {  // bf16(a)|bf16(b)<<16
    unsigned r;
    asm("v_cvt_pk_bf16_f32 %0, %1, %2" : "=v"(r) : "v"(a), "v"(b));
    return r;
}
union FU { bfrag v; unsigned u[4]; };

// 8 fp32 -> bf16 hi fragment + bf16 lo (residual) fragment
__device__ __forceinline__ void conv8(const float* f, bfrag& hi, bfrag& lo) {
    FU h, l;
#pragma unroll
    for (int m = 0; m < 4; ++m) {
        float a = f[2 * m], b = f[2 * m + 1];
        unsigned hp = cvtpk(a, b);
        float ra = a - __uint_as_float(hp << 16);
        float rb = b - __uint_as_float(hp & 0xFFFF0000u);
        h.u[m] = hp;
        l.u[m] = cvtpk(ra, rb);
    }
    hi = h.v;
    lo = l.v;
}

// --- kernel 0: codebook squared norms into ws (unchanged, proven) ---
__global__ __launch_bounds__(256) void cnorm_kernel(const float* __restrict__ cb,
                                                    float* __restrict__ cnorm, int K) {
    int k = blockIdx.x * blockDim.x + threadIdx.x;
    if (k >= K) return;
    const float4* c = (const float4*)(cb + (size_t)k * D);
    float s0 = 0.f, s1 = 0.f, s2 = 0.f, s3 = 0.f;
#pragma unroll
    for (int i = 0; i < D / 4; ++i) {
        float4 v = c[i];
        s0 = fmaf(v.x, v.x, s0);
        s1 = fmaf(v.y, v.y, s1);
        s2 = fmaf(v.z, v.z, s2);
        s3 = fmaf(v.w, v.w, s3);
    }
    cnorm[k] = (s0 + s1) + (s2 + s3);
}

__global__ __launch_bounds__(NTH, 2) void vq_mfma(const float* __restrict__ x,
                                                  const float* __restrict__ cb,
                                                  const float* __restrict__ cnorm,
                                                  float* __restrict__ out,
                                                  int N, int K) {
    __shared__ short cbt[2][2][TC * D];  // [buf][hi/lo][code*128+k], 64 KB, swizzled
    __shared__ float cns[1024];
    __shared__ unsigned rmin[BR];        // running approx row-min (fenc encoded)
    __shared__ unsigned long long win[BR];
    __shared__ unsigned clist[LCAP];
    __shared__ int ccnt;

    const int tid = threadIdx.x;
    const int lane = tid & 63;
    const int wv = tid >> 6;
    const int wr = wv >> 1;   // row-group 0..3 (32 rows each)
    const int cw = wv & 1;    // code half within tile
    const int la = lane & 15;
    const int kg = lane >> 4; // 0..3
    const int row0 = blockIdx.x * BR;

    if (tid < BR) { rmin[tid] = 0xFF7FFFFFu; win[tid] = ~0ull; }
    if (tid == 0) ccnt = 0;
    for (int i = tid; i < K; i += NTH) cns[i] = cnorm[i];

    // ---- X fragments -> registers (A-frag: row=la, k=kg*8+j per 32-k step) ----
    bfrag xh[2][4], xl[2][4];
#pragma unroll
    for (int rf = 0; rf < 2; ++rf) {
        const int xrow = row0 + wr * 32 + rf * 16 + la;
        const float* xp = x + (size_t)xrow * D + kg * 8;
#pragma unroll
        for (int ks = 0; ks < 4; ++ks) {
            float v[8];
            float4 f0 = *(const float4*)(xp + ks * 32);
            float4 f1 = *(const float4*)(xp + ks * 32 + 4);
            v[0] = f0.x; v[1] = f0.y; v[2] = f0.z; v[3] = f0.w;
            v[4] = f1.x; v[5] = f1.y; v[6] = f1.z; v[7] = f1.w;
            conv8(v, xh[rf][ks], xl[rf][ks]);
        }
    }

    // ---- codebook tile staging (global fp32 -> regs -> bf16 split -> LDS) ----
    const int scode = tid >> 3;  // 0..63
    const int dseg = tid & 7;    // 16-dim segment
    auto stage_load = [&](int t, float4* g) {
        const float* src = cb + (size_t)(t * TC + scode) * D + dseg * 16;
        g[0] = *(const float4*)(src);
        g[1] = *(const float4*)(src + 4);
        g[2] = *(const float4*)(src + 8);
        g[3] = *(const float4*)(src + 12);
    };
    auto stage_write = [&](int buf, const float4* g) {
        float v[16] = {g[0].x, g[0].y, g[0].z, g[0].w, g[1].x, g[1].y, g[1].z, g[1].w,
                       g[2].x, g[2].y, g[2].z, g[2].w, g[3].x, g[3].y, g[3].z, g[3].w};
        bfrag h0, l0, h1, l1;
        conv8(v, h0, l0);
        conv8(v + 8, h1, l1);
        const int a0 = ((scode << 8) + dseg * 32) ^ ((scode & 7) << 4);  // T2 swizzle
        const int a1 = a0 ^ 16;  // +16 within same 32B: XOR-safe since bit4 differs only
        char* ph = (char*)&cbt[buf][0][0];
        char* pl = (char*)&cbt[buf][1][0];
        *(bfrag*)(ph + (((scode << 8) + dseg * 32) ^ ((scode & 7) << 4))) = h0;
        *(bfrag*)(ph + (((scode << 8) + dseg * 32 + 16) ^ ((scode & 7) << 4))) = h1;
        *(bfrag*)(pl + (((scode << 8) + dseg * 32) ^ ((scode & 7) << 4))) = l0;
        *(bfrag*)(pl + (((scode << 8) + dseg * 32 + 16) ^ ((scode & 7) << 4))) = l1;
        (void)a0; (void)a1;
    };

    float4 g[4];
    {
        float4 g0[4];
        stage_load(0, g0);
        stage_write(0, g0);
    }
    stage_load(1, g);
    __syncthreads();

    const int cbase = cw * 32;
    for (int t = 0; t < NTILE; ++t) {
        const int buf = t & 1;
        // ---- compute: 4 k-steps x (2 rf x 2 cf x 3 split-terms) = 48 MFMA ----
        f32x4 acc[2][2] = {{{0.f, 0.f, 0.f, 0.f}, {0.f, 0.f, 0.f, 0.f}},
                           {{0.f, 0.f, 0.f, 0.f}, {0.f, 0.f, 0.f, 0.f}}};
        const char* ph = (const char*)&cbt[buf][0][0];
        const char* pl = (const char*)&cbt[buf][1][0];
#pragma unroll
        for (int ks = 0; ks < 4; ++ks) {
            const int kb = 64 * ks + 16 * kg;
            bfrag bh[2], bl[2];
#pragma unroll
            for (int cf = 0; cf < 2; ++cf) {
                const int code = cbase + cf * 16 + la;
                const int a = ((code << 8) + kb) ^ ((code & 7) << 4);
                bh[cf] = *(const bfrag*)(ph + a);
                bl[cf] = *(const bfrag*)(pl + a);
            }
#pragma unroll
            for (int rf = 0; rf < 2; ++rf)
#pragma unroll
                for (int cf = 0; cf < 2; ++cf) {
                    acc[rf][cf] = __builtin_amdgcn_mfma_f32_16x16x32_bf16(
                        xh[rf][ks], bh[cf], acc[rf][cf], 0, 0, 0);
                    acc[rf][cf] = __builtin_amdgcn_mfma_f32_16x16x32_bf16(
                        xh[rf][ks], bl[cf], acc[rf][cf], 0, 0, 0);
                    acc[rf][cf] = __builtin_amdgcn_mfma_f32_16x16x32_bf16(
                        xl[rf][ks], bh[cf], acc[rf][cf], 0, 0, 0);
                }
        }

        // ---- epilogue: dists, row-group min, margin-test append ----
        // C/D layout (m89): col(code)=la, row=(kg*4+i)
        const int c0 = t * TC + cbase + la;
        const int c1 = c0 + 16;
        const float cn0 = cns[c0], cn1 = cns[c1];
#pragma unroll
        for (int rf = 0; rf < 2; ++rf) {
            float d0[4], d1[4], m[4];
#pragma unroll
            for (int i = 0; i < 4; ++i) {
                d0[i] = fmaf(-2.f, acc[rf][0][i], cn0);
                d1[i] = fmaf(-2.f, acc[rf][1][i], cn1);
                m[i] = fminf(d0[i], d1[i]);
            }
#pragma unroll
            for (int i = 0; i < 4; ++i)
#pragma unroll
                for (int off = 1; off <= 8; off <<= 1)
                    m[i] = fminf(m[i], __shfl_xor(m[i], off));
#pragma unroll
            for (int i = 0; i < 4; ++i) {
                const int row = wr * 32 + rf * 16 + kg * 4 + i;
                // stale-high rowmin is safe (superset append); m[i] covers this tile
                const float thr = fminf(fdec(rmin[row]), m[i]) + MARGIN;
                if (d0[i] < thr) {
                    int p = atomicAdd(&ccnt, 1);
                    if (p < LCAP) clist[p] = (unsigned)((row << 10) | c0);
                }
                if (d1[i] < thr) {
                    int p = atomicAdd(&ccnt, 1);
                    if (p < LCAP) clist[p] = (unsigned)((row << 10) | c1);
                }
                if (la == 0) atomicMin(&rmin[row], fenc(m[i]));
            }
        }

        // ---- T14 staging: write tile t+1 (regs->LDS), then issue t+2 loads ----
        if (t + 1 < NTILE) {
            stage_write(buf ^ 1, g);
            if (t + 2 < NTILE) stage_load(t + 2, g);
        }
        __syncthreads();
    }

    // ---- exact fp32 recheck of candidates; packed atomicMin keeps lowest idx ----
    const int nc = (ccnt > LCAP) ? LCAP : ccnt;
    for (int b = wv * 4 + kg; b < nc; b += 32) {  // one candidate per 16-lane group
        const unsigned e = clist[b];
        const int row = e >> 10, code = e & 1023;
        const float4* xr4 = (const float4*)(x + (size_t)(row0 + row) * D + la * 8);
        const float4* cr4 = (const float4*)(cb + (size_t)code * D + la * 8);
        float4 a0 = xr4[0], a1 = xr4[1], b0 = cr4[0], b1 = cr4[1];
        float s = a0.x * b0.x;
        s = fmaf(a0.y, b0.y, s); s = fmaf(a0.z, b0.z, s); s = fmaf(a0.w, b0.w, s);
        s = fmaf(a1.x, b1.x, s); s = fmaf(a1.y, b1.y, s);
        s = fmaf(a1.z, b1.z, s); s = fmaf(a1.w, b1.w, s);
#pragma unroll
        for (int off = 1; off <= 8; off <<= 1) s += __shfl_xor(s, off);
        const float dist = fmaf(-2.f, s, cns[code]);
        if (la == 0)
            atomicMin(&win[row], ((unsigned long long)fenc(dist) << 32) | (unsigned)code);
    }
    __syncthreads();

    // ---- gather: out[row] = cb[winner] (coalesced float4) ----
    {
        const int r = tid >> 2, q = tid & 3;
        const int idx = (int)(win[r] & 0xFFFFFFFFull);
        const float4* cs = (const float4*)(cb + (size_t)idx * D + q * 32);
        float4* od = (float4*)(out + (size_t)(row0 + r) * D + q * 32);
#pragma unroll
        for (int i = 0; i < 8; ++i) od[i] = cs[i];
    }
}

extern "C" void kernel_launch(void* const* d_in, const int* in_sizes, int n_in,
                              void* d_out, int out_size, void* d_ws, size_t ws_size,
                              hipStream_t stream) {
    const float* x = (const float*)d_in[0];
    const float* cb = (const float*)d_in[1];
    float* out = (float*)d_out;
    const int N = in_sizes[0] / D;
    const int K = in_sizes[1] / D;
    float* cnorm = (float*)d_ws;  // K floats

    hipLaunchKernelGGL(cnorm_kernel, dim3((K + 255) / 256), dim3(256), 0, stream,
                       cb, cnorm, K);
    hipLaunchKernelGGL(vq_mfma, dim3(N / BR), dim3(NTH), 0, stream,
                       x, cb, cnorm, out, N, K);
}